// Round 2
// baseline (302.982 us; speedup 1.0000x reference)
//
#include <hip/hip_runtime.h>
#include <hip/hip_bf16.h>
#include <cstdint>

// DifferentiableILP on MI355X (gfx950).
// A = softmax(rule_weights[:,0,:]); 3x: facts = max(facts, colmax(A @ facts)).
// Columns independent -> each block owns a 64-col stripe; ft immutable in LDS,
// running col-max folded into the B fragment at load time (packed u16 max).
//
// R4 changes vs R3 (302us total, ilp 144us, MfmaUtil 30%, bank-conflict 4.65M):
//  - MFMA 16x16x32 -> 32x32x16 (2495 vs 2075 TF ubench): floor 50->41.5us,
//    halves MFMA instruction count (512->256/wave-iter) and frag registers.
//  - XOR swizzle key c&7 -> (c>>1)&7: stage writes / epilogue reads were 8-way
//    bank-conflicted (even cols only hit keys {0,2,4,6}); new key is
//    conflict-free for stage/epilogue AND keeps bF reads at the 8-group spread.
//  - k-loop keeps RAW bR double-buffered; fold with ml happens on bR[cur]
//    (loaded a full k-step ago -> no lgkm wait before the MFMA cluster).
//    Wrap prefetch at kt=31 now feeds next iteration directly (raw = valid).

typedef __attribute__((ext_vector_type(8))) short bf16x8;   // 8 bf16 = 4 VGPRs
typedef __attribute__((ext_vector_type(8))) unsigned short u16x8;
typedef __attribute__((ext_vector_type(16))) float f32x16;  // 32x32 accumulator
typedef unsigned short ushort_t;
typedef unsigned int uint32;

#define PDIM 512
#define CDIM 65536
#define NT   64      // columns per block

__device__ __forceinline__ ushort_t f2bf(float x) {          // RNE float->bf16
    uint32 u = __float_as_uint(x);
    return (ushort_t)((u + 0x7fffu + ((u >> 16) & 1u)) >> 16);
}
__device__ __forceinline__ float bf2f(uint32 bits) { return __uint_as_float(bits << 16); }

// packed max(v, splat(mu)) in the u16 domain (valid: all values are nonneg bf16)
__device__ __forceinline__ bf16x8 pkmax8(bf16x8 v, ushort_t mu) {
    u16x8 a = __builtin_bit_cast(u16x8, v);
    const u16x8 mb = {mu, mu, mu, mu, mu, mu, mu, mu};
    a = __builtin_elementwise_max(a, mb);
    return __builtin_bit_cast(bf16x8, a);
}

// ---- phase 1: softmax row r, packed fragment-linear for 32x32x16 MFMA.
// A-frag: lane reads A[row = wr*32 + (l&31)][k = kt2*16 + (l>>5)*8 .. +7]
// chunk idx16 = (kt2*16 + wr)*64 + (l>>5)*32 + (l&31)  -> 1KB contiguous per
// (kt2, wr) group, one dwordx4 per lane with imm offsets per row-tile.
__global__ __launch_bounds__(64) void softmax_pack(const float* __restrict__ rw,
                                                   ushort_t* __restrict__ Apk) {
    const int r  = blockIdx.x;
    const int ln = threadIdx.x;
    const float* row = rw + r * PDIM;
    float4 x0 = *(const float4*)(row + ln * 8);
    float4 x1 = *(const float4*)(row + ln * 8 + 4);
    float v[8] = {x0.x, x0.y, x0.z, x0.w, x1.x, x1.y, x1.z, x1.w};

    float mx = -1e30f;
    #pragma unroll
    for (int i = 0; i < 8; ++i) mx = fmaxf(mx, v[i]);
    #pragma unroll
    for (int d = 1; d < 64; d <<= 1) mx = fmaxf(mx, __shfl_xor(mx, d, 64));
    float s = 0.f;
    #pragma unroll
    for (int i = 0; i < 8; ++i) { v[i] = __expf(v[i] - mx); s += v[i]; }
    #pragma unroll
    for (int d = 1; d < 64; d <<= 1) s += __shfl_xor(s, d, 64);
    const float inv = 1.f / s;

    ushort_t o[8];
    #pragma unroll
    for (int i = 0; i < 8; ++i) o[i] = f2bf(v[i] * inv);
    // lane holds k-chunk kh = ln (k = ln*8..+7): kt2 = ln>>1, halfsel = ln&1
    const int idx16 = ((ln >> 1) * 16 + (r >> 5)) * 64 + ((ln & 1) << 5) + (r & 31);
    *(int4*)(Apk + idx16 * 8) = *(const int4*)o;
}

// ---- phase 2: per-64-column stripe, fused multi-iteration fixpoint.
// LDS ft[c][p] bf16; granule (8 p = 16B) at element offset p0 ^ (((c>>1)&7)<<3).
__global__ __launch_bounds__(256, 2) void ilp_kernel(
        const float* __restrict__ facts,
        const ushort_t* __restrict__ Apk,
        const int* __restrict__ n_iter_p,
        float* __restrict__ out) {
    __shared__ ushort_t ft[NT * PDIM];     // 65536 B
    __shared__ float wred[2][4][NT];       // 2048 B: per-wave colmax partials, dbuf
    __shared__ float mfin[NT];             // 256 B: final column max for epilogue

    const int tid  = threadIdx.x;
    const int wave = tid >> 6;
    const int lane = tid & 63;
    const int l31  = lane & 31;
    const int half = lane >> 5;
    const int c0   = blockIdx.x * NT;

    int n_iter = *n_iter_p;                // issue scalar load early
    n_iter = n_iter < 0 ? 0 : (n_iter > 8 ? 8 : n_iter);

    // ---- stage: ft[c][p] = bf16(facts[p][c0+c]); float2 -> 2 cols per lane.
    // key (c>>1)&7 shared by the col pair: 32 lanes sweep all 8 bank groups.
    {
        const int ch  = (tid & 31) * 2;
        const int pb  = tid >> 5;
        const int key = ((ch >> 1) & 7) << 3;
        #pragma unroll 4
        for (int s = 0; s < 8; ++s) {
            const int p0 = s * 64 + pb * 8;
            ushort_t ga[8], gb[8];
            #pragma unroll
            for (int i = 0; i < 8; ++i) {
                const float2 v = *(const float2*)(facts + (p0 + i) * CDIM + c0 + ch);
                ga[i] = f2bf(v.x);
                gb[i] = f2bf(v.y);
            }
            *(int4*)(&ft[ch * PDIM + (p0 ^ key)])       = *(const int4*)ga;
            *(int4*)(&ft[(ch + 1) * PDIM + (p0 ^ key)]) = *(const int4*)gb;
        }
    }
    __syncthreads();

    // per-wave GEMM bases (element offsets)
    const ushort_t* abase = Apk + (wave * 256 + half * 32 + l31) * 8;  // +kt2*8192 +rt2*512
    int cbase2[2], ckey2[2];
    #pragma unroll
    for (int ct2 = 0; ct2 < 2; ++ct2) {
        const int c = ct2 * 32 + l31;
        cbase2[ct2] = c * PDIM;
        ckey2[ct2]  = ((c >> 1) & 7) << 3;
    }

    ushort_t ml[2] = {0, 0};               // running colmax, bf16 bits
    float    mf[2] = {0.f, 0.f};           // running colmax, f32

    bf16x8 aF[2][4], bR[2][2];             // bR = RAW (unfolded) B fragments
    {   // prologue: kt2 = 0
        #pragma unroll
        for (int rt2 = 0; rt2 < 4; ++rt2) aF[0][rt2] = *(const bf16x8*)(abase + rt2 * 512);
        const int gh = half * 8;
        #pragma unroll
        for (int ct2 = 0; ct2 < 2; ++ct2)
            bR[0][ct2] = *(const bf16x8*)(&ft[cbase2[ct2] + (gh ^ ckey2[ct2])]);
    }

    #pragma unroll 1
    for (int it = 0; it < n_iter; ++it) {
        f32x16 acc[4][2];
        #pragma unroll
        for (int rt2 = 0; rt2 < 4; ++rt2)
            #pragma unroll
            for (int ct2 = 0; ct2 < 2; ++ct2)
                #pragma unroll
                for (int e = 0; e < 16; ++e) acc[rt2][ct2][e] = 0.f;

        #pragma unroll 2
        for (int kt2 = 0; kt2 < 32; ++kt2) {
            const int cur = kt2 & 1, nxt = cur ^ 1;
            const int ktn = (kt2 + 1) & 31;         // kt2=31 wraps: feeds next iter
            {   // prefetch next A frags (L2-resident Apk)
                const ushort_t* ap = abase + ktn * 8192;
                #pragma unroll
                for (int rt2 = 0; rt2 < 4; ++rt2)
                    aF[nxt][rt2] = *(const bf16x8*)(ap + rt2 * 512);
            }
            {   // prefetch next raw B frags (ds_read_b128, conflict-free)
                const int gh = (ktn * 2 + half) * 8;
                #pragma unroll
                for (int ct2 = 0; ct2 < 2; ++ct2)
                    bR[nxt][ct2] = *(const bf16x8*)(&ft[cbase2[ct2] + (gh ^ ckey2[ct2])]);
            }
            // fold running colmax into cur B (inputs ready: loaded last k-step)
            bf16x8 bC[2];
            #pragma unroll
            for (int ct2 = 0; ct2 < 2; ++ct2) bC[ct2] = pkmax8(bR[cur][ct2], ml[ct2]);

            __builtin_amdgcn_s_setprio(1);
            #pragma unroll
            for (int rt2 = 0; rt2 < 4; ++rt2)
                #pragma unroll
                for (int ct2 = 0; ct2 < 2; ++ct2)
                    acc[rt2][ct2] = __builtin_amdgcn_mfma_f32_32x32x16_bf16(
                        aF[cur][rt2], bC[ct2], acc[rt2][ct2], 0, 0, 0);
            __builtin_amdgcn_s_setprio(0);
        }

        // ---- colmax fold (D: col=lane&31, rows over regs + lane-half)
        float mx[2];
        #pragma unroll
        for (int ct2 = 0; ct2 < 2; ++ct2) {
            float m0 = -1e30f;
            #pragma unroll
            for (int rt2 = 0; rt2 < 4; ++rt2)
                #pragma unroll
                for (int e = 0; e < 16; ++e) m0 = fmaxf(m0, acc[rt2][ct2][e]);
            m0 = fmaxf(m0, __shfl_xor(m0, 32, 64));
            mx[ct2] = m0;
        }
        const int buf = it & 1;
        if (half == 0) {
            #pragma unroll
            for (int ct2 = 0; ct2 < 2; ++ct2) wred[buf][wave][ct2 * 32 + l31] = mx[ct2];
        }
        __syncthreads();
        #pragma unroll
        for (int ct2 = 0; ct2 < 2; ++ct2) {
            const int c = ct2 * 32 + l31;
            const float m = fmaxf(fmaxf(wred[buf][0][c], wred[buf][1][c]),
                                  fmaxf(wred[buf][2][c], wred[buf][3][c]));
            mf[ct2] = fmaxf(mf[ct2], m);    // monotone guard vs bf16 wobble
            ml[ct2] = f2bf(mf[ct2]);
        }
        // no second barrier: wred double-buffered (next write to this buf is
        // beyond the NEXT iteration's barrier, after all reads above).
    }

    // ---- publish final m per column for epilogue layout
    if (wave == 0 && half == 0) {
        #pragma unroll
        for (int ct2 = 0; ct2 < 2; ++ct2) mfin[ct2 * 32 + l31] = mf[ct2];
    }
    __syncthreads();

    // ---- epilogue: out = max(ft, m_final); float2 stores, 2 cols per lane
    {
        const int ch  = (tid & 31) * 2;
        const int pb  = tid >> 5;
        const int key = ((ch >> 1) & 7) << 3;
        const float ma = mfin[ch];
        const float mb = mfin[ch + 1];
        for (int s = 0; s < 8; ++s) {
            const int p0 = s * 64 + pb * 8;
            ushort_t ga[8], gb[8];
            *(int4*)ga = *(const int4*)(&ft[ch * PDIM + (p0 ^ key)]);
            *(int4*)gb = *(const int4*)(&ft[(ch + 1) * PDIM + (p0 ^ key)]);
            #pragma unroll
            for (int i = 0; i < 8; ++i) {
                float2 v;
                v.x = fmaxf(bf2f(ga[i]), ma);
                v.y = fmaxf(bf2f(gb[i]), mb);
                *(float2*)(out + (p0 + i) * CDIM + c0 + ch) = v;
            }
        }
    }
}

extern "C" void kernel_launch(void* const* d_in, const int* in_sizes, int n_in,
                              void* d_out, int out_size, void* d_ws, size_t ws_size,
                              hipStream_t stream) {
    const float* facts    = (const float*)d_in[0];       // [512, 65536] fp32
    const float* rw       = (const float*)d_in[1];       // [512, 1, 512] fp32
    const int*   n_iter_p = (const int*)d_in[2];         // scalar 3
    float* out = (float*)d_out;

    ushort_t* Apk = (ushort_t*)d_ws;                     // 512 KB

    softmax_pack<<<PDIM, 64, 0, stream>>>(rw, Apk);
    ilp_kernel<<<CDIM / NT, 256, 0, stream>>>(facts, Apk, n_iter_p, out);
}